// Round 14
// baseline (325.412 us; speedup 1.0000x reference)
//
#include <hip/hip_runtime.h>

#define N_NODES   100000
#define N_EDGES   1600000
#define DIM       128
#define NUM_LAYERS 3

#define NB   391          // buckets of 256 dst-nodes
#define BCAP 8192         // staging capacity per bucket (mean 4092, sigma 64)
#define NT   13           // src tiles: src>>13 -> 0..12

typedef __attribute__((ext_vector_type(8))) short short8;
typedef __attribute__((ext_vector_type(4))) float f32x4;

// Builtin MFMA only: compiler handles MFMA hazards/regalloc. The inline-asm
// variant caused 4 schedule-dependent corruptions (r7-r11); r13 A/B proved it.
#define MFMA_BF16(acc, a, b) \
    acc = __builtin_amdgcn_mfma_f32_16x16x32_bf16(a, b, acc, 0, 0, 0)

__device__ __forceinline__ unsigned short f2bf(float f) {
    unsigned int u = __builtin_bit_cast(unsigned int, f);
    unsigned int r = (u + 0x7FFFu + ((u >> 16) & 1u)) >> 16;   // RNE
    return (unsigned short)r;
}
__device__ __forceinline__ float bflo(unsigned int p) {
    return __builtin_bit_cast(float, p << 16);
}
__device__ __forceinline__ float bfhi(unsigned int p) {
    return __builtin_bit_cast(float, p & 0xFFFF0000u);
}

// ---------------- prep: x f32->bf16 and weight shuffle, one kernel ----------------

__global__ void k_prep(const float* __restrict__ x, unsigned short* __restrict__ xb,
                       const float* __restrict__ W1, const float* __restrict__ W2,
                       unsigned short* __restrict__ wb) {
    int bidx = blockIdx.x;
    int tid  = threadIdx.x;
    if (bidx < 12500) {
        int i = bidx * 256 + tid;
        float4 v = ((const float4*)x)[i];
        uint2 o;
        o.x = (unsigned int)f2bf(v.x) | ((unsigned int)f2bf(v.y) << 16);
        o.y = (unsigned int)f2bf(v.z) | ((unsigned int)f2bf(v.w) << 16);
        ((uint2*)xb)[i] = o;
    } else {
        int o = (bidx - 12500) * 256 + tid;     // 6*16384 total
        int m   = o >> 14;
        int idx = o & 16383;
        int i    = idx & 7;
        int lane = (idx >> 3) & 63;
        int kk   = (idx >> 9) & 3;
        int t    = idx >> 11;
        int k = kk * 32 + (lane >> 4) * 8 + i;
        int n = t * 16 + (lane & 15);
        const float* Wsrc = (m < 3) ? (W1 + (size_t)m * 16384) : (W2 + (size_t)(m - 3) * 16384);
        wb[o] = f2bf(Wsrc[k * 128 + n]);
    }
}

// ---------------- CSR build ----------------
// gcur[b] starts at 0 (memset) and counts records in bucket b; staging slot =
// b*BCAP + reservation. k_build computes its own exclusive base from gcur.

__global__ __launch_bounds__(1024) void k_bin(
        const int* __restrict__ src, const int* __restrict__ dst,
        int* __restrict__ gcur, unsigned int* __restrict__ staging) {
    __shared__ int h[NB];
    __shared__ int base[NB];
    int tid = threadIdx.x;
    for (int i = tid; i < NB; i += 1024) h[i] = 0;
    __syncthreads();
    int e0 = blockIdx.x * 16384;
    unsigned int rec[16];
    int bk[16];
    #pragma unroll
    for (int k = 0; k < 16; ++k) {
        int e = e0 + k * 1024 + tid;
        if (e < N_EDGES) {
            int d = dst[e];
            int b = d >> 8;
            bk[k] = b;
            rec[k] = (unsigned int)src[e] | ((unsigned int)(d & 255) << 17);
            atomicAdd(&h[b], 1);
        } else bk[k] = -1;
    }
    __syncthreads();
    for (int i = tid; i < NB; i += 1024) {
        int c = h[i];
        base[i] = (c > 0) ? (i * BCAP + atomicAdd(&gcur[i], c)) : 0;
    }
    __syncthreads();
    for (int i = tid; i < NB; i += 1024) h[i] = 0;
    __syncthreads();
    #pragma unroll
    for (int k = 0; k < 16; ++k) {
        if (bk[k] >= 0) {
            int p = base[bk[k]] + atomicAdd(&h[bk[k]], 1);
            staging[p] = rec[k];
        }
    }
}

// Per bucket: in-kernel exclusive bucket base (sum of gcur[0..b)), per-(node,
// src-tile) hist -> per-node scan -> tile-major scatter into compact ss.
__global__ __launch_bounds__(256) void k_build(
        const unsigned int* __restrict__ staging, const int* __restrict__ gcur,
        int* __restrict__ offs, int* __restrict__ ss) {
    __shared__ int h2[256][NT];
    __shared__ int s[256];
    __shared__ int red[256];
    int b = blockIdx.x, t = threadIdx.x;
    // ebase = sum_{i<b} gcur[i]
    int t2 = t + 256;
    int v0 = (t  < b) ? gcur[t]  : 0;
    int v1 = (t2 < b) ? gcur[t2] : 0;   // b <= 390 < 512; t2 < b implies t2 < NB
    red[t] = v0 + v1;
    __syncthreads();
    for (int off = 128; off > 0; off >>= 1) {
        if (t < off) red[t] += red[t + off];
        __syncthreads();
    }
    int eb  = red[0];
    int cnt = gcur[b];
    const unsigned int* seg = staging + (size_t)b * BCAP;
    #pragma unroll
    for (int i = 0; i < NT; ++i) h2[t][i] = 0;
    __syncthreads();
    for (int i = t; i < cnt; i += 256) {
        unsigned int r = seg[i];
        atomicAdd(&h2[r >> 17][(r & 0x1FFFFu) >> 13], 1);
    }
    __syncthreads();
    int c = 0;
    #pragma unroll
    for (int i = 0; i < NT; ++i) c += h2[t][i];
    s[t] = c;
    __syncthreads();
    for (int off = 1; off < 256; off <<= 1) {
        int tmp = 0;
        if (t >= off) tmp = s[t - off];
        __syncthreads();
        if (t >= off) s[t] += tmp;
        __syncthreads();
    }
    int excl = eb + s[t] - c;
    offs[b * 256 + t] = excl;
    int run = excl;
    #pragma unroll
    for (int i = 0; i < NT; ++i) { int cc = h2[t][i]; h2[t][i] = run; run += cc; }
    __syncthreads();
    for (int i = t; i < cnt; i += 256) {
        unsigned int r = seg[i];
        int sv = (int)(r & 0x1FFFFu);
        int pos = atomicAdd(&h2[r >> 17][sv >> 13], 1);
        ss[pos] = sv;
    }
}

// ---------------- Aggregation (round-12 exact, at its ~3 TB/s wall — FROZEN) ----------------

__global__ void k_agg(const unsigned short* __restrict__ xb, const int* __restrict__ offs,
                      const int* __restrict__ ss, unsigned short* __restrict__ hb) {
    int g    = threadIdx.x >> 5;
    int lane = threadIdx.x & 31;
    int node = blockIdx.x * 8 + g;
    uint2 sv = *(const uint2*)(xb + (size_t)node * DIM + lane * 4);
    float a0 = bflo(sv.x), a1 = bfhi(sv.x), a2 = bflo(sv.y), a3 = bfhi(sv.y);
    int start = offs[node];
    int end   = offs[node + 1];
    for (int e = start; e < end; e += 16) {
        int  sdx[16];
        #pragma unroll
        for (int j = 0; j < 16; ++j) {
            int p = e + j;
            sdx[j] = ss[p < end ? p : end - 1];
        }
        uint2 vv[16];
        #pragma unroll
        for (int j = 0; j < 16; ++j)
            vv[j] = *(const uint2*)(xb + (size_t)sdx[j] * DIM + lane * 4);
        #pragma unroll
        for (int j = 0; j < 16; ++j) {
            bool m = (e + j) < end;
            unsigned int vx = m ? vv[j].x : 0u;
            unsigned int vy = m ? vv[j].y : 0u;
            a0 += bflo(vx); a1 += bfhi(vx);
            a2 += bflo(vy); a3 += bfhi(vy);
        }
    }
    uint2 o;
    o.x = (unsigned int)f2bf(a0) | ((unsigned int)f2bf(a1) << 16);
    o.y = (unsigned int)f2bf(a2) | ((unsigned int)f2bf(a3) << 16);
    *(uint2*)(hb + (size_t)node * DIM + lane * 4) = o;
}

// ---------------- MFMA MLP: 32 rows/wave + LDS-staged weights (builtin MFMA) ----------------
// 4 waves x 32 rows = 128 rows/block, grid 782. W1 staged in 32 KB LDS ->
// GEMM1 -> barrier -> W2 restaged -> GEMM2. Per-wave weight reload halved vs
// 16-row; per-layer staging traffic 100 -> 50 MB. Reads clamped, stores masked.

template <int FINAL>
__global__ __launch_bounds__(256) void k_mlp(
        const unsigned short* __restrict__ hb,
        const unsigned short* __restrict__ w1b, const float* __restrict__ b1,
        const unsigned short* __restrict__ w2b, const float* __restrict__ b2,
        unsigned short* __restrict__ outb, float* __restrict__ outf) {
    __shared__ __align__(16) unsigned short Ws[16384];     // 32 KB: W1, then W2
    __shared__ __align__(16) unsigned short Ts[4][32][136];
    int tid  = threadIdx.x;
    int w    = tid >> 6;
    int lane = tid & 63;
    int lrow = lane & 15;
    int lgrp = lane >> 4;
    int r0   = blockIdx.x * 128 + w * 32;
    int rA = min(r0 + lrow,      N_NODES - 1);   // read-clamped; stores masked
    int rB = min(r0 + 16 + lrow, N_NODES - 1);

    const short8* hb8 = (const short8*)hb;
    const short8* wsf = (const short8*)Ws;

    // prefetch both half-tiles' A fragments before staging (latency overlap)
    short8 aLo[4], aHi[4];
    #pragma unroll
    for (int kk = 0; kk < 4; ++kk) {
        aLo[kk] = hb8[(size_t)rA * 16 + kk * 4 + lgrp];
        aHi[kk] = hb8[(size_t)rB * 16 + kk * 4 + lgrp];
    }

    {   // stage W1: 2048 uint4 by 256 threads x 8
        const uint4* srcp = (const uint4*)w1b;
        uint4* dstp = (uint4*)Ws;
        #pragma unroll
        for (int i = 0; i < 8; ++i) dstp[tid + 256 * i] = srcp[tid + 256 * i];
    }
    __syncthreads();

    f32x4 acc[2][8];
    #pragma unroll
    for (int hf = 0; hf < 2; ++hf)
        #pragma unroll
        for (int t = 0; t < 8; ++t) acc[hf][t] = (f32x4){0.f, 0.f, 0.f, 0.f};

    #pragma unroll
    for (int kk = 0; kk < 4; ++kk) {
        const short8* bp = wsf + kk * 64 + lane;
        #pragma unroll
        for (int t = 0; t < 8; ++t) {
            short8 b = bp[t * 256];
            MFMA_BF16(acc[0][t], aLo[kk], b);
            MFMA_BF16(acc[1][t], aHi[kk], b);
        }
    }

    #pragma unroll
    for (int hf = 0; hf < 2; ++hf)
        #pragma unroll
        for (int t = 0; t < 8; ++t) {
            float bb = b1[t * 16 + lrow];
            #pragma unroll
            for (int r = 0; r < 4; ++r) {
                float v = acc[hf][t][r] + bb;
                v = fmaxf(v, 0.f);
                Ts[w][hf * 16 + lgrp * 4 + r][t * 16 + lrow] = f2bf(v);
            }
            acc[hf][t] = (f32x4){0.f, 0.f, 0.f, 0.f};
        }
    __syncthreads();   // all GEMM1 reads of Ws done; Ts written

    {   // stage W2 over the same LDS
        const uint4* srcp = (const uint4*)w2b;
        uint4* dstp = (uint4*)Ws;
        #pragma unroll
        for (int i = 0; i < 8; ++i) dstp[tid + 256 * i] = srcp[tid + 256 * i];
    }
    __syncthreads();

    #pragma unroll
    for (int kk = 0; kk < 4; ++kk) {
        short8 a2Lo = *(const short8*)&Ts[w][lrow][kk * 32 + lgrp * 8];
        short8 a2Hi = *(const short8*)&Ts[w][16 + lrow][kk * 32 + lgrp * 8];
        const short8* bp = wsf + kk * 64 + lane;
        #pragma unroll
        for (int t = 0; t < 8; ++t) {
            short8 b = bp[t * 256];
            MFMA_BF16(acc[0][t], a2Lo, b);
            MFMA_BF16(acc[1][t], a2Hi, b);
        }
    }

    #pragma unroll
    for (int hf = 0; hf < 2; ++hf)
        #pragma unroll
        for (int t = 0; t < 8; ++t) {
            float bb = b2[t * 16 + lrow];
            #pragma unroll
            for (int r = 0; r < 4; ++r) {
                float v = acc[hf][t][r] + bb;
                int row = r0 + hf * 16 + lgrp * 4 + r;
                if (row < N_NODES) {
                    size_t oi = (size_t)row * DIM + t * 16 + lrow;
                    if (FINAL) outf[oi] = v;
                    else       outb[oi] = f2bf(fmaxf(v, 0.f));
                }
            }
        }
}

// ---------------- launch ----------------

extern "C" void kernel_launch(void* const* d_in, const int* in_sizes, int n_in,
                              void* d_out, int out_size, void* d_ws, size_t ws_size,
                              hipStream_t stream) {
    const float* x  = (const float*)d_in[0];
    const int*   ei = (const int*)d_in[1];
    const float* W1 = (const float*)d_in[2];
    const float* b1 = (const float*)d_in[3];
    const float* W2 = (const float*)d_in[4];
    const float* b2 = (const float*)d_in[5];
    float* out = (float*)d_out;

    const int* src = ei;
    const int* dst = ei + N_EDGES;

    char* ws = (char*)d_ws;
    int* gcur  = (int*)ws; ws += 2048;
    int* offs  = (int*)ws; ws += 100352 * 4;
    int* ss    = (int*)ws; ws += (size_t)N_EDGES * 4;
    unsigned short* wb = (unsigned short*)ws; ws += 6 * 16384 * 2;
    unsigned short* hb = (unsigned short*)ws;
    unsigned int* staging = (unsigned int*)hb;          // aliases hb, dead before first k_agg
    ws += (size_t)N_NODES * DIM * 2;
    unsigned short* xb = (unsigned short*)ws; ws += (size_t)N_NODES * DIM * 2;

    // prep + CSR build (10 launches total incl. memset)
    hipMemsetAsync(gcur, 0, NB * 4, stream);
    k_prep <<<12884, 256, 0, stream>>>(x, xb, W1, W2, wb);
    k_bin  <<<98, 1024, 0, stream>>>(src, dst, gcur, staging);
    k_build<<<NB, 256, 0, stream>>>(staging, gcur, offs, ss);

    // 3 GIN layers: agg(xb -> hb), mlp(hb -> xb or out)
    for (int l = 0; l < NUM_LAYERS; ++l) {
        k_agg<<<12500, 256, 0, stream>>>(xb, offs, ss, hb);
        const unsigned short* w1l = wb + (size_t)l * 16384;
        const unsigned short* w2l = wb + (size_t)(3 + l) * 16384;
        const float* b1l = b1 + (size_t)l * DIM;
        const float* b2l = b2 + (size_t)l * DIM;
        if (l < NUM_LAYERS - 1)
            k_mlp<0><<<782, 256, 0, stream>>>(hb, w1l, b1l, w2l, b2l, xb, nullptr);
        else
            k_mlp<1><<<782, 256, 0, stream>>>(hb, w1l, b1l, w2l, b2l, nullptr, out);
    }
}

// Round 15
// 298.414 us; speedup vs baseline: 1.0905x; 1.0905x over previous
//
#include <hip/hip_runtime.h>

#define N_NODES   100000
#define N_EDGES   1600000
#define DIM       128
#define NUM_LAYERS 3

#define NB   391          // buckets of 256 dst-nodes
#define BCAP 8192         // staging capacity per bucket (mean 4092, sigma 64)
#define NT   13           // src tiles: src>>13 -> 0..12

typedef __attribute__((ext_vector_type(8))) short short8;
typedef __attribute__((ext_vector_type(4))) float f32x4;

// Builtin MFMA only: compiler handles MFMA hazards/regalloc. The inline-asm
// variant caused 4 schedule-dependent corruptions (r7-r11); r13 A/B proved it.
#define MFMA_BF16(acc, a, b) \
    acc = __builtin_amdgcn_mfma_f32_16x16x32_bf16(a, b, acc, 0, 0, 0)

__device__ __forceinline__ unsigned short f2bf(float f) {
    unsigned int u = __builtin_bit_cast(unsigned int, f);
    unsigned int r = (u + 0x7FFFu + ((u >> 16) & 1u)) >> 16;   // RNE
    return (unsigned short)r;
}
__device__ __forceinline__ float bflo(unsigned int p) {
    return __builtin_bit_cast(float, p << 16);
}
__device__ __forceinline__ float bfhi(unsigned int p) {
    return __builtin_bit_cast(float, p & 0xFFFF0000u);
}

// ---------------- prep: x f32->bf16 and weight shuffle, one kernel (r14, PASSED) ----------------

__global__ void k_prep(const float* __restrict__ x, unsigned short* __restrict__ xb,
                       const float* __restrict__ W1, const float* __restrict__ W2,
                       unsigned short* __restrict__ wb) {
    int bidx = blockIdx.x;
    int tid  = threadIdx.x;
    if (bidx < 12500) {
        int i = bidx * 256 + tid;
        float4 v = ((const float4*)x)[i];
        uint2 o;
        o.x = (unsigned int)f2bf(v.x) | ((unsigned int)f2bf(v.y) << 16);
        o.y = (unsigned int)f2bf(v.z) | ((unsigned int)f2bf(v.w) << 16);
        ((uint2*)xb)[i] = o;
    } else {
        int o = (bidx - 12500) * 256 + tid;     // 6*16384 total
        int m   = o >> 14;
        int idx = o & 16383;
        int i    = idx & 7;
        int lane = (idx >> 3) & 63;
        int kk   = (idx >> 9) & 3;
        int t    = idx >> 11;
        int k = kk * 32 + (lane >> 4) * 8 + i;
        int n = t * 16 + (lane & 15);
        const float* Wsrc = (m < 3) ? (W1 + (size_t)m * 16384) : (W2 + (size_t)(m - 3) * 16384);
        wb[o] = f2bf(Wsrc[k * 128 + n]);
    }
}

// ---------------- CSR build (r14, PASSED) ----------------

__global__ __launch_bounds__(1024) void k_bin(
        const int* __restrict__ src, const int* __restrict__ dst,
        int* __restrict__ gcur, unsigned int* __restrict__ staging) {
    __shared__ int h[NB];
    __shared__ int base[NB];
    int tid = threadIdx.x;
    for (int i = tid; i < NB; i += 1024) h[i] = 0;
    __syncthreads();
    int e0 = blockIdx.x * 16384;
    unsigned int rec[16];
    int bk[16];
    #pragma unroll
    for (int k = 0; k < 16; ++k) {
        int e = e0 + k * 1024 + tid;
        if (e < N_EDGES) {
            int d = dst[e];
            int b = d >> 8;
            bk[k] = b;
            rec[k] = (unsigned int)src[e] | ((unsigned int)(d & 255) << 17);
            atomicAdd(&h[b], 1);
        } else bk[k] = -1;
    }
    __syncthreads();
    for (int i = tid; i < NB; i += 1024) {
        int c = h[i];
        base[i] = (c > 0) ? (i * BCAP + atomicAdd(&gcur[i], c)) : 0;
    }
    __syncthreads();
    for (int i = tid; i < NB; i += 1024) h[i] = 0;
    __syncthreads();
    #pragma unroll
    for (int k = 0; k < 16; ++k) {
        if (bk[k] >= 0) {
            int p = base[bk[k]] + atomicAdd(&h[bk[k]], 1);
            staging[p] = rec[k];
        }
    }
}

__global__ __launch_bounds__(256) void k_build(
        const unsigned int* __restrict__ staging, const int* __restrict__ gcur,
        int* __restrict__ offs, int* __restrict__ ss) {
    __shared__ int h2[256][NT];
    __shared__ int s[256];
    __shared__ int red[256];
    int b = blockIdx.x, t = threadIdx.x;
    // ebase = sum_{i<b} gcur[i]
    int t2 = t + 256;
    int v0 = (t  < b) ? gcur[t]  : 0;
    int v1 = (t2 < b) ? gcur[t2] : 0;
    red[t] = v0 + v1;
    __syncthreads();
    for (int off = 128; off > 0; off >>= 1) {
        if (t < off) red[t] += red[t + off];
        __syncthreads();
    }
    int eb  = red[0];
    int cnt = gcur[b];
    const unsigned int* seg = staging + (size_t)b * BCAP;
    #pragma unroll
    for (int i = 0; i < NT; ++i) h2[t][i] = 0;
    __syncthreads();
    for (int i = t; i < cnt; i += 256) {
        unsigned int r = seg[i];
        atomicAdd(&h2[r >> 17][(r & 0x1FFFFu) >> 13], 1);
    }
    __syncthreads();
    int c = 0;
    #pragma unroll
    for (int i = 0; i < NT; ++i) c += h2[t][i];
    s[t] = c;
    __syncthreads();
    for (int off = 1; off < 256; off <<= 1) {
        int tmp = 0;
        if (t >= off) tmp = s[t - off];
        __syncthreads();
        if (t >= off) s[t] += tmp;
        __syncthreads();
    }
    int excl = eb + s[t] - c;
    offs[b * 256 + t] = excl;
    int run = excl;
    #pragma unroll
    for (int i = 0; i < NT; ++i) { int cc = h2[t][i]; h2[t][i] = run; run += cc; }
    __syncthreads();
    for (int i = t; i < cnt; i += 256) {
        unsigned int r = seg[i];
        int sv = (int)(r & 0x1FFFFu);
        int pos = atomicAdd(&h2[r >> 17][sv >> 13], 1);
        ss[pos] = sv;
    }
}

// ---------------- Aggregation (FROZEN at its ~3 TB/s L2-miss wall) ----------------

__global__ void k_agg(const unsigned short* __restrict__ xb, const int* __restrict__ offs,
                      const int* __restrict__ ss, unsigned short* __restrict__ hb) {
    int g    = threadIdx.x >> 5;
    int lane = threadIdx.x & 31;
    int node = blockIdx.x * 8 + g;
    uint2 sv = *(const uint2*)(xb + (size_t)node * DIM + lane * 4);
    float a0 = bflo(sv.x), a1 = bfhi(sv.x), a2 = bflo(sv.y), a3 = bfhi(sv.y);
    int start = offs[node];
    int end   = offs[node + 1];
    for (int e = start; e < end; e += 16) {
        int  sdx[16];
        #pragma unroll
        for (int j = 0; j < 16; ++j) {
            int p = e + j;
            sdx[j] = ss[p < end ? p : end - 1];
        }
        uint2 vv[16];
        #pragma unroll
        for (int j = 0; j < 16; ++j)
            vv[j] = *(const uint2*)(xb + (size_t)sdx[j] * DIM + lane * 4);
        #pragma unroll
        for (int j = 0; j < 16; ++j) {
            bool m = (e + j) < end;
            unsigned int vx = m ? vv[j].x : 0u;
            unsigned int vy = m ? vv[j].y : 0u;
            a0 += bflo(vx); a1 += bfhi(vx);
            a2 += bflo(vy); a3 += bfhi(vy);
        }
    }
    uint2 o;
    o.x = (unsigned int)f2bf(a0) | ((unsigned int)f2bf(a1) << 16);
    o.y = (unsigned int)f2bf(a2) | ((unsigned int)f2bf(a3) << 16);
    *(uint2*)(hb + (size_t)node * DIM + lane * 4) = o;
}

// ---------------- MFMA MLP (r13 exact: 16 rows/wave, LDS-staged weights, grid 1563) ----------------
// r14's 32-row variant regressed (66.8 KB LDS -> 8 waves/CU); this is the
// proven best: 49.4 KB LDS -> 3 blocks/CU = 12 waves/CU, k_mlp ~17-21 us.

template <int FINAL>
__global__ __launch_bounds__(256) void k_mlp(
        const unsigned short* __restrict__ hb,
        const unsigned short* __restrict__ w1b, const float* __restrict__ b1,
        const unsigned short* __restrict__ w2b, const float* __restrict__ b2,
        unsigned short* __restrict__ outb, float* __restrict__ outf) {
    __shared__ __align__(16) unsigned short Ws[16384];   // 32 KB: W1, then W2
    __shared__ __align__(16) unsigned short Ts[4][16][136];
    int tid  = threadIdx.x;
    int w    = tid >> 6;
    int lane = tid & 63;
    int r0   = blockIdx.x * 64 + w * 16;
    bool live = (r0 < N_NODES);
    if (!live) r0 = N_NODES - 16;
    int lrow = lane & 15;
    int lgrp = lane >> 4;

    const short8* hb8 = (const short8*)hb;
    const short8* wsf = (const short8*)Ws;

    // prefetch this wave's A fragments before staging (latency overlap)
    short8 a_pre[4];
    #pragma unroll
    for (int kk = 0; kk < 4; ++kk)
        a_pre[kk] = hb8[(size_t)(r0 + lrow) * 16 + kk * 4 + lgrp];

    {   // stage W1: 2048 uint4 by 256 threads x 8
        const uint4* srcp = (const uint4*)w1b;
        uint4* dstp = (uint4*)Ws;
        #pragma unroll
        for (int i = 0; i < 8; ++i) dstp[tid + 256 * i] = srcp[tid + 256 * i];
    }
    __syncthreads();

    f32x4 acc[8];
    #pragma unroll
    for (int t = 0; t < 8; ++t) acc[t] = (f32x4){0.f, 0.f, 0.f, 0.f};

    #pragma unroll
    for (int kk = 0; kk < 4; ++kk) {
        short8 a = a_pre[kk];
        const short8* bp = wsf + kk * 64 + lane;
        #pragma unroll
        for (int t = 0; t < 8; ++t) {
            short8 b = bp[t * 256];
            MFMA_BF16(acc[t], a, b);
        }
    }

    #pragma unroll
    for (int t = 0; t < 8; ++t) {
        float bb = b1[t * 16 + lrow];
        #pragma unroll
        for (int r = 0; r < 4; ++r) {
            float v = acc[t][r] + bb;
            v = fmaxf(v, 0.f);
            Ts[w][lgrp * 4 + r][t * 16 + lrow] = f2bf(v);
        }
        acc[t] = (f32x4){0.f, 0.f, 0.f, 0.f};
    }
    __syncthreads();   // all GEMM1 reads of Ws done; Ts written

    {   // stage W2 over the same LDS
        const uint4* srcp = (const uint4*)w2b;
        uint4* dstp = (uint4*)Ws;
        #pragma unroll
        for (int i = 0; i < 8; ++i) dstp[tid + 256 * i] = srcp[tid + 256 * i];
    }
    __syncthreads();

    #pragma unroll
    for (int kk = 0; kk < 4; ++kk) {
        short8 a = *(const short8*)&Ts[w][lrow][kk * 32 + lgrp * 8];
        const short8* bp = wsf + kk * 64 + lane;
        #pragma unroll
        for (int t = 0; t < 8; ++t) {
            short8 b = bp[t * 256];
            MFMA_BF16(acc[t], a, b);
        }
    }

    #pragma unroll
    for (int t = 0; t < 8; ++t) {
        float bb = b2[t * 16 + lrow];
        #pragma unroll
        for (int r = 0; r < 4; ++r) {
            float v = acc[t][r] + bb;
            size_t oi = (size_t)(r0 + lgrp * 4 + r) * DIM + t * 16 + lrow;
            if (FINAL) {
                if (live) outf[oi] = v;
            } else {
                v = fmaxf(v, 0.f);
                if (live) outb[oi] = f2bf(v);
            }
        }
    }
}

// ---------------- launch ----------------

extern "C" void kernel_launch(void* const* d_in, const int* in_sizes, int n_in,
                              void* d_out, int out_size, void* d_ws, size_t ws_size,
                              hipStream_t stream) {
    const float* x  = (const float*)d_in[0];
    const int*   ei = (const int*)d_in[1];
    const float* W1 = (const float*)d_in[2];
    const float* b1 = (const float*)d_in[3];
    const float* W2 = (const float*)d_in[4];
    const float* b2 = (const float*)d_in[5];
    float* out = (float*)d_out;

    const int* src = ei;
    const int* dst = ei + N_EDGES;

    char* ws = (char*)d_ws;
    int* gcur  = (int*)ws; ws += 2048;
    int* offs  = (int*)ws; ws += 100352 * 4;
    int* ss    = (int*)ws; ws += (size_t)N_EDGES * 4;
    unsigned short* wb = (unsigned short*)ws; ws += 6 * 16384 * 2;
    unsigned short* hb = (unsigned short*)ws;
    unsigned int* staging = (unsigned int*)hb;          // aliases hb, dead before first k_agg
    ws += (size_t)N_NODES * DIM * 2;
    unsigned short* xb = (unsigned short*)ws; ws += (size_t)N_NODES * DIM * 2;

    // prep + CSR build
    hipMemsetAsync(gcur, 0, NB * 4, stream);
    k_prep <<<12884, 256, 0, stream>>>(x, xb, W1, W2, wb);
    k_bin  <<<98, 1024, 0, stream>>>(src, dst, gcur, staging);
    k_build<<<NB, 256, 0, stream>>>(staging, gcur, offs, ss);

    // 3 GIN layers: agg(xb -> hb), mlp(hb -> xb or out)
    for (int l = 0; l < NUM_LAYERS; ++l) {
        k_agg<<<12500, 256, 0, stream>>>(xb, offs, ss, hb);
        const unsigned short* w1l = wb + (size_t)l * 16384;
        const unsigned short* w2l = wb + (size_t)(3 + l) * 16384;
        const float* b1l = b1 + (size_t)l * DIM;
        const float* b2l = b2 + (size_t)l * DIM;
        if (l < NUM_LAYERS - 1)
            k_mlp<0><<<1563, 256, 0, stream>>>(hb, w1l, b1l, w2l, b2l, xb, nullptr);
        else
            k_mlp<1><<<1563, 256, 0, stream>>>(hb, w1l, b1l, w2l, b2l, nullptr, out);
    }
}